// Round 16
// baseline (226.383 us; speedup 1.0000x reference)
//
#include <hip/hip_runtime.h>
#include <hip/hip_bf16.h>
#include <stdint.h>

typedef float f32x4 __attribute__((ext_vector_type(4)));
typedef float f32x16 __attribute__((ext_vector_type(16)));
typedef __bf16 bf16x8 __attribute__((ext_vector_type(8)));
typedef uint32_t u32;
typedef u32 u32x4 __attribute__((ext_vector_type(4)));

#define SCALE 0.35355339059327378f    // 64^-0.25
#define SCALE2 0.42466090014400953f   // 64^-0.25 * sqrt(log2(e)) -> exp2 domain
#define LOG2E 1.4426950408889634f

// hazard-safe exp2: compiler-emitted v_exp_f32 (TRANS-op wait states handled).
// NOTE: raw inline-asm v_exp_f32 caused deterministic corruption (R6-R8 vs R10/R11 A/B).
#if __has_builtin(__builtin_amdgcn_exp2f)
__device__ __forceinline__ float exp2fast(float x) { return __builtin_amdgcn_exp2f(x); }
#else
__device__ __forceinline__ float exp2fast(float x) { return exp2f(x); }
#endif

__device__ __forceinline__ u32 packbf2(float a, float b) {
  u32 ua = __builtin_bit_cast(u32, a);
  u32 ub = __builtin_bit_cast(u32, b);
  ua = (ua + 0x7fffu + ((ua >> 16) & 1u)) >> 16;
  ub = (ub + 0x7fffu + ((ub >> 16) & 1u)) >> 16;
  return ua | (ub << 16);
}
__device__ __forceinline__ unsigned short tobf(float a) {
  u32 ua = __builtin_bit_cast(u32, a);
  return (unsigned short)((ua + 0x7fffu + ((ua >> 16) & 1u)) >> 16);
}
__device__ __forceinline__ u32 pk2(float a, float b) {
  unsigned short lo = __builtin_bit_cast(unsigned short, (__bf16)a);
  unsigned short hi = __builtin_bit_cast(unsigned short, (__bf16)b);
  return (u32)lo | ((u32)hi << 16);
}
__device__ __forceinline__ int swz(int row, int col) {  // prep-kernel swizzle (8-row stripe)
  return row * 64 + (col ^ ((row & 7) << 3));
}
__device__ __forceinline__ void gload16(const void* g, void* l) {
  __builtin_amdgcn_global_load_lds((const __attribute__((address_space(1))) void*)g,
                                   (__attribute__((address_space(3))) void*)l, 16, 0, 0);
}
__device__ __forceinline__ f32x16 zero16() {
  f32x16 z;
#pragma unroll
  for (int i = 0; i < 16; ++i) z[i] = 0.f;
  return z;
}

// ============ pre-pass: fp32 qkv -> bf16 ws =============================
// ws (shorts): Qs[32][2048][64] | Ks[32][2048][64] | Vs[32][64][2048]
__global__ __launch_bounds__(256) void prep_kernel(const float* __restrict__ qkv,
                                                   unsigned short* __restrict__ ws) {
  __shared__ unsigned short tq[64 * 64];
  __shared__ unsigned short tk[64 * 64];
  const int tid = threadIdx.x;
  const int bid = blockIdx.x;          // 0..1023
  const int bh = bid >> 5;
  const int tile = bid & 31;
  const int b = bh >> 4, h = bh & 15;
  const float* hq = qkv + ((size_t)b * 3072 + (size_t)h * 192) * 2048;
  const int s0 = tile * 64;

  {
    const int c = tid >> 2;
    const int jj = (tid & 3) * 16;
    const float* qp = hq + (size_t)c * 2048 + s0 + jj;
    const float* kp = qp + 64 * 2048;
    const float* vp = qp + 128 * 2048;
    unsigned short* vout = ws + (size_t)64 * 131072 + (size_t)bh * 131072 +
                           (size_t)c * 2048 + s0 + jj;
    u32 vbuf[8];
#pragma unroll
    for (int u = 0; u < 4; ++u) {
      f32x4 fq = *(const f32x4*)(qp + u * 4);
      f32x4 fk = *(const f32x4*)(kp + u * 4);
      f32x4 fv = *(const f32x4*)(vp + u * 4);
#pragma unroll
      for (int e = 0; e < 4; ++e) {
        int s = jj + u * 4 + e;
        int sw = swz(s, c);
        tq[sw] = tobf(fq[e] * SCALE2);
        tk[sw] = tobf(fk[e] * SCALE2);
      }
      vbuf[2 * u]     = packbf2(fv[0], fv[1]);
      vbuf[2 * u + 1] = packbf2(fv[2], fv[3]);
    }
    *(u32x4*)(vout)     = *(u32x4*)&vbuf[0];
    *(u32x4*)(vout + 8) = *(u32x4*)&vbuf[4];
  }
  __syncthreads();
  {
    const int s = tid >> 2;
    const int c0 = (tid & 3) * 16;
    const int ch0 = (((c0 >> 3) ^ (s & 7)) << 3);
    const int ch1 = ((((c0 >> 3) + 1) ^ (s & 7)) << 3);
    size_t ob = (size_t)bh * 131072 + (size_t)(s0 + s) * 64 + c0;
    unsigned short* qout = ws + ob;
    unsigned short* kout = ws + (size_t)32 * 131072 + ob;
    *(u32x4*)qout       = *(u32x4*)&tq[s * 64 + ch0];
    *(u32x4*)(qout + 8) = *(u32x4*)&tq[s * 64 + ch1];
    *(u32x4*)kout       = *(u32x4*)&tk[s * 64 + ch0];
    *(u32x4*)(kout + 8) = *(u32x4*)&tk[s * 64 + ch1];
  }
}

// ============ attn16: no split-KV; 8 q-slots x 32 rows; 32KB LDS ========
// 256 blocks x 8 waves; each wave owns 32 q-rows, iterates all 32 KV tiles.
// K/V double-buffered in LDS (shared by all 8 waves), stripe-aware swizzle
// (conflict-free, R15-verified). No merge epilogue. 4 blocks/CU = 32 waves.
__global__ __launch_bounds__(512, 8) void attn16_kernel(const unsigned short* __restrict__ ws,
                                                        float* __restrict__ out) {
  // smem: [0,16K) K dbuf (buf*8K); [16K,32K) V dbuf (buf*8K)
  __shared__ __align__(16) char smem[32768];

  const int tid  = threadIdx.x;
  const int lane = tid & 63;
  const int wv   = tid >> 6;       // 0..7 (q-slot)
  const int l31  = lane & 31;
  const int hi   = lane >> 5;
  const int xr   = l31 & 7;
  const int xr2  = (l31 >> 3) & 3;           // stripe bits of the row being read

  const int bid = blockIdx.x;                    // 0..255
  const int bh  = (bid & 7) * 4 + ((bid >> 3) >> 3);
  const int qb  = (bid >> 3) & 7;                // 8 q-blocks of 256 rows
  const int b = bh >> 4, h = bh & 15;
  const int q0 = qb * 256;

  const unsigned short* Qs = ws + (size_t)bh * 131072;
  const unsigned short* Ks = ws + (size_t)32 * 131072 + (size_t)bh * 131072;
  const unsigned short* Vs = ws + (size_t)64 * 131072 + (size_t)bh * 131072;

  // Q as MFMA-B operand (persistent): lane: t=l31, c=kc*16+hi*8+j
  bf16x8 qB[4];
#pragma unroll
  for (int kc = 0; kc < 4; ++kc)
    qB[kc] = *(const bf16x8*)(Qs + (size_t)(q0 + wv * 32 + l31) * 64 + kc * 16 + hi * 8);

  // staging: wave wv stages rows wv*8 + srow (srow = lane>>3, 8 rows, 1KB each
  // of K and V per tile). Source chunk = (lane&7) ^ (row&7) ^ ((row>>3)&3);
  // LDS dest linear -> stripe-aware swizzle (R15: conflict-free).
  const int srow = lane >> 3;                    // 0..7
  const int sch  = (lane & 7) ^ srow ^ (wv & 3); // (row>>3)&3 == wv&3
  const char* kg = (const char*)Ks + (size_t)(wv * 8 + srow) * 128  + sch * 16;
  const char* vg = (const char*)Vs + (size_t)(wv * 8 + srow) * 4096 + sch * 16;
  char* kd = smem + wv * 1024;                   // + buf*8192
  char* vd = smem + 16384 + wv * 1024;           // + buf*8192

  f32x16 oacc0 = zero16(), oacc1 = zero16();
  float lrun = 0.f;

  { // prologue: stage tile 0 -> buf 0
    gload16(kg, kd);
    gload16(vg, vd);
  }

#pragma unroll 1
  for (int it = 0; it < 32; ++it) {
    const int cur = it & 1;
    __syncthreads();                 // tile it resident in buf[cur]; buf[cur^1] free
    if (it < 31) {                   // prefetch next tile
      gload16(kg + (size_t)(it + 1) * 8192, kd + (cur ^ 1) * 8192);
      gload16(vg + (size_t)(it + 1) * 128,  vd + (cur ^ 1) * 8192);
    }

    // ---- S^T = K Q : D[row=s][col=t] ----
    const unsigned short* kt = (const unsigned short*)(smem + cur * 8192);
    f32x16 a0 = zero16(), a1 = zero16();
    __builtin_amdgcn_s_setprio(1);
#pragma unroll
    for (int kc = 0; kc < 4; ++kc) {
      int chs = (((kc * 2 + hi) ^ xr ^ xr2)) << 3;
      bf16x8 kA0 = *(const bf16x8*)(kt + l31 * 64 + chs);
      bf16x8 kA1 = *(const bf16x8*)(kt + (32 + l31) * 64 + chs);
      a0 = __builtin_amdgcn_mfma_f32_32x32x16_bf16(kA0, qB[kc], a0, 0, 0, 0);
      a1 = __builtin_amdgcn_mfma_f32_32x32x16_bf16(kA1, qB[kc], a1, 0, 0, 0);
    }
    __builtin_amdgcn_s_setprio(0);

    // ---- no-max softmax (exp2 domain): p = exp2(s) directly ----
#pragma unroll
    for (int i = 0; i < 16; ++i) a0[i] = exp2fast(a0[i]);
#pragma unroll
    for (int i = 0; i < 16; ++i) a1[i] = exp2fast(a1[i]);
    {
      f32x16 s01 = a0 + a1;
      f32x4 s4;
#pragma unroll
      for (int i = 0; i < 4; ++i)
        s4[i] = (s01[i] + s01[i + 4]) + (s01[i + 8] + s01[i + 12]);
      lrun += (s4[0] + s4[1]) + (s4[2] + s4[3]);
    }

    // ---- P -> PV B-fragments (cvt_pk + permlane32_swap) ----
    bf16x8 pB[4];
#pragma unroll
    for (int sc = 0; sc < 4; ++sc) {
      const f32x16& src = (sc < 2) ? a0 : a1;
      const int rb = (sc & 1) * 8;
      u32 c01 = pk2(src[rb + 0], src[rb + 1]);
      u32 c23 = pk2(src[rb + 2], src[rb + 3]);
      u32 c45 = pk2(src[rb + 4], src[rb + 5]);
      u32 c67 = pk2(src[rb + 6], src[rb + 7]);
      asm volatile("v_permlane32_swap_b32 %0, %1" : "+v"(c01), "+v"(c45));
      asm volatile("v_permlane32_swap_b32 %0, %1" : "+v"(c23), "+v"(c67));
      u32x4 w = {c01, c23, c45, c67};
      pB[sc] = __builtin_bit_cast(bf16x8, w);
    }

    // ---- O^T += V P^T ----
    const unsigned short* vt = (const unsigned short*)(smem + 16384 + cur * 8192);
    __builtin_amdgcn_s_setprio(1);
#pragma unroll
    for (int sc = 0; sc < 4; ++sc) {
      int chs = (((sc * 2 + hi) ^ xr ^ xr2)) << 3;
      bf16x8 vA0 = *(const bf16x8*)(vt + l31 * 64 + chs);
      bf16x8 vA1 = *(const bf16x8*)(vt + (32 + l31) * 64 + chs);
      oacc0 = __builtin_amdgcn_mfma_f32_32x32x16_bf16(vA0, pB[sc], oacc0, 0, 0, 0);
      oacc1 = __builtin_amdgcn_mfma_f32_32x32x16_bf16(vA1, pB[sc], oacc1, 0, 0, 0);
    }
    __builtin_amdgcn_s_setprio(0);
  }

  // ---- epilogue: direct normalize + store (no merge) ----
  float lfull = lrun + __shfl_xor(lrun, 32);
  float inv = 1.0f / lfull;
  float* outp = out + ((size_t)b * 1024 + (size_t)h * 64) * 2048;
  const int t = q0 + wv * 32 + l31;
#pragma unroll
  for (int r = 0; r < 16; ++r) {
    int c = (r & 3) + 8 * (r >> 2) + 4 * hi;
    outp[(size_t)c * 2048 + t]        = oacc0[r] * inv;
    outp[(size_t)(c + 32) * 2048 + t] = oacc1[r] * inv;
  }
}

// ============ round-1 fallback (no workspace needed) ====================
__global__ __launch_bounds__(256) void qkv_attn_kernel(const float* __restrict__ qkv,
                                                       float* __restrict__ out) {
  __shared__ __align__(16) unsigned short s_kt[64 * 64];
  __shared__ __align__(16) unsigned short s_v [64 * 64];
  __shared__ __align__(16) unsigned short s_qp[128 * 64];

  const int tid  = threadIdx.x;
  const int lane = tid & 63;
  const int wv   = tid >> 6;
  const int l15  = lane & 15;
  const int lg   = lane >> 4;

  int bid = blockIdx.x;
  int bh  = (bid & 7) * 4 + ((bid >> 3) >> 4);
  int qb  = (bid >> 3) & 15;
  int b = bh >> 4, h = bh & 15;
  const float* __restrict__ hq = qkv + ((size_t)b * 3072 + (size_t)h * 192) * 2048;
  const int q0 = qb * 128;

  {
    int c  = (tid & 31) * 2;
    int tq = tid >> 5;
    const float* r0 = hq + (size_t)c * 2048 + q0;
    const float* r1 = r0 + 2048;
#pragma unroll
    for (int j = 0; j < 4; ++j) {
      int t4 = tq * 16 + j * 4;
      f32x4 f0 = *(const f32x4*)(r0 + t4);
      f32x4 f1 = *(const f32x4*)(r1 + t4);
#pragma unroll
      for (int e = 0; e < 4; ++e) {
        int t = t4 + e;
        ((u32*)s_qp)[swz(t, c) >> 1] = packbf2(f0[e] * SCALE, f1[e] * SCALE);
      }
    }
  }
  __syncthreads();

  bf16x8 qA[2][2];
#pragma unroll
  for (int tf = 0; tf < 2; ++tf)
#pragma unroll
    for (int kc = 0; kc < 2; ++kc) {
      int t  = wv * 32 + tf * 16 + l15;
      int c0 = kc * 32 + lg * 8;
      qA[tf][kc] = *(const bf16x8*)&s_qp[swz(t, c0)];
    }

  const f32x4 zf = {0.f, 0.f, 0.f, 0.f};
  f32x4 oacc[2][4];
#pragma unroll
  for (int tf = 0; tf < 2; ++tf)
#pragma unroll
    for (int cs = 0; cs < 4; ++cs) oacc[tf][cs] = zf;
  float mrun[2][4], lrun[2][4];
#pragma unroll
  for (int tf = 0; tf < 2; ++tf)
#pragma unroll
    for (int r = 0; r < 4; ++r) { mrun[tf][r] = -1e30f; lrun[tf][r] = 0.f; }

  const int pw = wv * 2048;

  for (int st = 0; st < 32; ++st) {
    const int s0g = st * 64;
    __syncthreads();
    {
      int c  = (tid & 31) * 2;
      int tq = tid >> 5;
      const float* r0 = hq + (size_t)(64 + c) * 2048 + s0g;
      const float* r1 = r0 + 2048;
#pragma unroll
      for (int j = 0; j < 2; ++j) {
        int s4 = tq * 8 + j * 4;
        f32x4 f0 = *(const f32x4*)(r0 + s4);
        f32x4 f1 = *(const f32x4*)(r1 + s4);
#pragma unroll
        for (int e = 0; e < 4; ++e)
          ((u32*)s_kt)[swz(s4 + e, c) >> 1] = packbf2(f0[e] * SCALE, f1[e] * SCALE);
      }
    }
    {
      int c  = tid >> 2;
      int sq = tid & 3;
      const float* rv = hq + (size_t)(128 + c) * 2048 + s0g;
#pragma unroll
      for (int j = 0; j < 4; ++j) {
        int s4 = sq * 16 + j * 4;
        f32x4 f = *(const f32x4*)(rv + s4);
        int si = swz(c, s4) >> 1;
        ((u32*)s_v)[si]     = packbf2(f[0], f[1]);
        ((u32*)s_v)[si + 1] = packbf2(f[2], f[3]);
      }
    }
    __syncthreads();

    f32x4 acc[2][4];
#pragma unroll
    for (int tf = 0; tf < 2; ++tf)
#pragma unroll
      for (int ss = 0; ss < 4; ++ss) acc[tf][ss] = zf;
#pragma unroll
    for (int kc = 0; kc < 2; ++kc) {
#pragma unroll
      for (int ss = 0; ss < 4; ++ss) {
        int srow = ss * 16 + l15;
        int c0   = kc * 32 + lg * 8;
        bf16x8 kB = *(const bf16x8*)&s_kt[swz(srow, c0)];
#pragma unroll
        for (int tf = 0; tf < 2; ++tf)
          acc[tf][ss] = __builtin_amdgcn_mfma_f32_16x16x32_bf16(qA[tf][kc], kB, acc[tf][ss], 0, 0, 0);
      }
    }

#pragma unroll
    for (int tf = 0; tf < 2; ++tf) {
#pragma unroll
      for (int r = 0; r < 4; ++r) {
        float tm = fmaxf(fmaxf(acc[tf][0][r], acc[tf][1][r]),
                         fmaxf(acc[tf][2][r], acc[tf][3][r]));
#pragma unroll
        for (int off = 1; off < 16; off <<= 1) tm = fmaxf(tm, __shfl_xor(tm, off));
        float mold = mrun[tf][r];
        float mnew = fmaxf(mold, tm);
        float rs   = exp2f((mold - mnew) * LOG2E);
        mrun[tf][r] = mnew;
        int t = tf * 16 + lg * 4 + r;
        float psum = 0.f;
#pragma unroll
        for (int ss = 0; ss < 4; ++ss) {
          float p = exp2f((acc[tf][ss][r] - mnew) * LOG2E);
          psum += p;
          s_qp[pw + swz(t, ss * 16 + l15)] = tobf(p);
        }
        lrun[tf][r] = lrun[tf][r] * rs + psum;
#pragma unroll
        for (int cs = 0; cs < 4; ++cs) oacc[tf][cs][r] *= rs;
      }
    }

    bf16x8 pA[2][2];
#pragma unroll
    for (int tf = 0; tf < 2; ++tf)
#pragma unroll
      for (int kc = 0; kc < 2; ++kc) {
        int t  = tf * 16 + l15;
        int s0 = kc * 32 + lg * 8;
        pA[tf][kc] = *(const bf16x8*)&s_qp[pw + swz(t, s0)];
      }
#pragma unroll
    for (int cs = 0; cs < 4; ++cs) {
#pragma unroll
      for (int kc = 0; kc < 2; ++kc) {
        int crow = cs * 16 + l15;
        int s0   = kc * 32 + lg * 8;
        bf16x8 vB = *(const bf16x8*)&s_v[swz(crow, s0)];
#pragma unroll
        for (int tf = 0; tf < 2; ++tf)
          oacc[tf][cs] = __builtin_amdgcn_mfma_f32_16x16x32_bf16(pA[tf][kc], vB, oacc[tf][cs], 0, 0, 0);
      }
    }
  }

  float* outp = out + ((size_t)b * 1024 + (size_t)h * 64) * 2048;
#pragma unroll
  for (int tf = 0; tf < 2; ++tf) {
    f32x4 invv;
#pragma unroll
    for (int r = 0; r < 4; ++r) {
      float ls = lrun[tf][r];
#pragma unroll
      for (int off = 1; off < 16; off <<= 1) ls += __shfl_xor(ls, off);
      invv[r] = 1.0f / ls;
    }
#pragma unroll
    for (int cs = 0; cs < 4; ++cs) {
      int c = cs * 16 + l15;
      float* po = outp + (size_t)c * 2048 + q0 + wv * 32 + tf * 16 + lg * 4;
      f32x4 o = oacc[tf][cs] * invv;
      *(f32x4*)po = o;
    }
  }
}

extern "C" void kernel_launch(void* const* d_in, const int* in_sizes, int n_in,
                              void* d_out, int out_size, void* d_ws, size_t ws_size,
                              hipStream_t stream) {
  (void)in_sizes; (void)n_in; (void)out_size;
  const float* qkv = (const float*)d_in[0];
  float* outp = (float*)d_out;
  const size_t need = (size_t)96 * 131072 * 2;  // 25.2 MB bf16 workspace
  if (ws_size >= need && d_ws != nullptr) {
    unsigned short* ws = (unsigned short*)d_ws;
    prep_kernel<<<dim3(1024), dim3(256), 0, stream>>>(qkv, ws);
    attn16_kernel<<<dim3(256), dim3(512), 0, stream>>>(ws, outp);
  } else {
    qkv_attn_kernel<<<dim3(512), dim3(256), 0, stream>>>(qkv, outp);
  }
}

// Round 17
// 85.228 us; speedup vs baseline: 2.6562x; 2.6562x over previous
//
#include <hip/hip_runtime.h>
#include <hip/hip_bf16.h>
#include <stdint.h>

typedef float f32x4 __attribute__((ext_vector_type(4)));
typedef float f32x16 __attribute__((ext_vector_type(16)));
typedef __bf16 bf16x8 __attribute__((ext_vector_type(8)));
typedef uint32_t u32;
typedef u32 u32x4 __attribute__((ext_vector_type(4)));

#define SCALE 0.35355339059327378f    // 64^-0.25
#define SCALE2 0.42466090014400953f   // 64^-0.25 * sqrt(log2(e)) -> exp2 domain
#define LOG2E 1.4426950408889634f

// hazard-safe exp2: compiler-emitted v_exp_f32 (TRANS-op wait states handled).
// NOTE: raw inline-asm v_exp_f32 caused deterministic corruption (R6-R8 vs R10/R11 A/B).
#if __has_builtin(__builtin_amdgcn_exp2f)
__device__ __forceinline__ float exp2fast(float x) { return __builtin_amdgcn_exp2f(x); }
#else
__device__ __forceinline__ float exp2fast(float x) { return exp2f(x); }
#endif

__device__ __forceinline__ u32 packbf2(float a, float b) {
  u32 ua = __builtin_bit_cast(u32, a);
  u32 ub = __builtin_bit_cast(u32, b);
  ua = (ua + 0x7fffu + ((ua >> 16) & 1u)) >> 16;
  ub = (ub + 0x7fffu + ((ub >> 16) & 1u)) >> 16;
  return ua | (ub << 16);
}
__device__ __forceinline__ unsigned short tobf(float a) {
  u32 ua = __builtin_bit_cast(u32, a);
  return (unsigned short)((ua + 0x7fffu + ((ua >> 16) & 1u)) >> 16);
}
__device__ __forceinline__ u32 pk2(float a, float b) {
  unsigned short lo = __builtin_bit_cast(unsigned short, (__bf16)a);
  unsigned short hi = __builtin_bit_cast(unsigned short, (__bf16)b);
  return (u32)lo | ((u32)hi << 16);
}
__device__ __forceinline__ int swz(int row, int col) {  // prep-kernel swizzle (8-row stripe)
  return row * 64 + (col ^ ((row & 7) << 3));
}
__device__ __forceinline__ void gload16(const void* g, void* l) {
  __builtin_amdgcn_global_load_lds((const __attribute__((address_space(1))) void*)g,
                                   (__attribute__((address_space(3))) void*)l, 16, 0, 0);
}
__device__ __forceinline__ f32x16 zero16() {
  f32x16 z;
#pragma unroll
  for (int i = 0; i < 16; ++i) z[i] = 0.f;
  return z;
}

// ============ pre-pass: fp32 qkv -> bf16 ws =============================
// ws (shorts): Qs[32][2048][64] | Ks[32][2048][64] | Vs[32][64][2048]
__global__ __launch_bounds__(256) void prep_kernel(const float* __restrict__ qkv,
                                                   unsigned short* __restrict__ ws) {
  __shared__ unsigned short tq[64 * 64];
  __shared__ unsigned short tk[64 * 64];
  const int tid = threadIdx.x;
  const int bid = blockIdx.x;          // 0..1023
  const int bh = bid >> 5;
  const int tile = bid & 31;
  const int b = bh >> 4, h = bh & 15;
  const float* hq = qkv + ((size_t)b * 3072 + (size_t)h * 192) * 2048;
  const int s0 = tile * 64;

  {
    const int c = tid >> 2;
    const int jj = (tid & 3) * 16;
    const float* qp = hq + (size_t)c * 2048 + s0 + jj;
    const float* kp = qp + 64 * 2048;
    const float* vp = qp + 128 * 2048;
    unsigned short* vout = ws + (size_t)64 * 131072 + (size_t)bh * 131072 +
                           (size_t)c * 2048 + s0 + jj;
    u32 vbuf[8];
#pragma unroll
    for (int u = 0; u < 4; ++u) {
      f32x4 fq = *(const f32x4*)(qp + u * 4);
      f32x4 fk = *(const f32x4*)(kp + u * 4);
      f32x4 fv = *(const f32x4*)(vp + u * 4);
#pragma unroll
      for (int e = 0; e < 4; ++e) {
        int s = jj + u * 4 + e;
        int sw = swz(s, c);
        tq[sw] = tobf(fq[e] * SCALE2);
        tk[sw] = tobf(fk[e] * SCALE2);
      }
      vbuf[2 * u]     = packbf2(fv[0], fv[1]);
      vbuf[2 * u + 1] = packbf2(fv[2], fv[3]);
    }
    *(u32x4*)(vout)     = *(u32x4*)&vbuf[0];
    *(u32x4*)(vout + 8) = *(u32x4*)&vbuf[4];
  }
  __syncthreads();
  {
    const int s = tid >> 2;
    const int c0 = (tid & 3) * 16;
    const int ch0 = (((c0 >> 3) ^ (s & 7)) << 3);
    const int ch1 = ((((c0 >> 3) + 1) ^ (s & 7)) << 3);
    size_t ob = (size_t)bh * 131072 + (size_t)(s0 + s) * 64 + c0;
    unsigned short* qout = ws + ob;
    unsigned short* kout = ws + (size_t)32 * 131072 + ob;
    *(u32x4*)qout       = *(u32x4*)&tq[s * 64 + ch0];
    *(u32x4*)(qout + 8) = *(u32x4*)&tq[s * 64 + ch1];
    *(u32x4*)kout       = *(u32x4*)&tk[s * 64 + ch0];
    *(u32x4*)(kout + 8) = *(u32x4*)&tk[s * 64 + ch1];
  }
}

// ============ attn17: no split-KV, KVBLK=128 (2 subtiles / barrier) =====
// 256 blocks x 8 waves; each wave owns 32 q-rows; 16 iterations of 128 kv.
// K[2][128][64], V[2][64][128] in LDS (64KB), stripe-aware swizzle.
// 17 barriers total (vs 33), no merge epilogue. 2 blocks/CU = 16 waves.
__global__ __launch_bounds__(512, 4) void attn17_kernel(const unsigned short* __restrict__ ws,
                                                        float* __restrict__ out) {
  // smem: [0,32K) K dbuf (buf*16K); [32K,64K) V dbuf (buf*16K)
  __shared__ __align__(16) char smem[65536];

  const int tid  = threadIdx.x;
  const int lane = tid & 63;
  const int wv   = tid >> 6;       // 0..7 (q-slot)
  const int l31  = lane & 31;
  const int hi   = lane >> 5;
  const int xr   = l31 & 7;
  const int xr2  = (l31 >> 3) & 3;           // stripe bits of the row being read

  const int bid = blockIdx.x;                    // 0..255
  const int bh  = (bid & 7) * 4 + ((bid >> 3) >> 3);
  const int qb  = (bid >> 3) & 7;                // 8 q-blocks of 256 rows
  const int b = bh >> 4, h = bh & 15;
  const int q0 = qb * 256;

  const unsigned short* Qs = ws + (size_t)bh * 131072;
  const unsigned short* Ks = ws + (size_t)32 * 131072 + (size_t)bh * 131072;
  const unsigned short* Vs = ws + (size_t)64 * 131072 + (size_t)bh * 131072;

  // Q as MFMA-B operand (persistent): lane: t=l31, c=kc*16+hi*8+j
  bf16x8 qB[4];
#pragma unroll
  for (int kc = 0; kc < 4; ++kc)
    qB[kc] = *(const bf16x8*)(Qs + (size_t)(q0 + wv * 32 + l31) * 64 + kc * 16 + hi * 8);

  // ---- staging pointers ----
  // K tile rows r = 0..127 (128B each). Wave wv stages rows wv*16+srow (A)
  // and +8 (B); source chunk = (lane&7) ^ (r&7) ^ ((r>>3)&3).
  const int srow = lane >> 3;                    // 0..7
  const int schA = (lane & 7) ^ srow ^ ((2 * wv) & 3);
  const int schB = schA ^ 1;
  const char* kgA = (const char*)Ks + (size_t)(wv * 16 + srow) * 128     + schA * 16;
  const char* kgB = (const char*)Ks + (size_t)(wv * 16 + 8 + srow) * 128 + schB * 16;
  // V tile [64 rows][128 cols] (256B/row, 16 chunks). Wave wv stages rows
  // wv*8 + (lane>>4) (A: 4 rows) and +4 (B); source chunk (lane&15) ^ sw(c).
  const int r4  = lane >> 4;                     // 0..3
  const int swA = r4 ^ (wv & 3);                 // sw for rows wv*8+r4
  const char* vgA = (const char*)Vs + (size_t)(wv * 8 + r4) * 4096     + (((lane & 15) ^ swA) * 16);
  const char* vgB = (const char*)Vs + (size_t)(wv * 8 + 4 + r4) * 4096 + (((lane & 15) ^ swA ^ 4) * 16);
  char* kd = smem + wv * 2048;                   // + buf*16384 (+1024 for B)
  char* vd = smem + 32768 + wv * 2048;           // + buf*16384 (+1024 for B)

  f32x16 oacc0 = zero16(), oacc1 = zero16();
  float lrun = 0.f;

  auto STAGE = [&](int it, int buf) {            // stage 128-kv tile `it` -> buf
    const size_t ko = (size_t)it * 16384;        // 128 rows * 128 B
    const size_t vo = (size_t)it * 256;          // 128 cols * 2 B
    char* kdn = kd + buf * 16384;
    char* vdn = vd + buf * 16384;
    gload16(kgA + ko, kdn);
    gload16(kgB + ko, kdn + 1024);
    gload16(vgA + vo, vdn);
    gload16(vgB + vo, vdn + 1024);
  };

  STAGE(0, 0);

#pragma unroll 1
  for (int it = 0; it < 16; ++it) {
    const int cur = it & 1;
    __syncthreads();                 // tile it resident in buf[cur]; buf[cur^1] free
    if (it < 15) STAGE(it + 1, cur ^ 1);

    const unsigned short* kt = (const unsigned short*)(smem + cur * 16384);
    const unsigned short* vt = (const unsigned short*)(smem + 32768 + cur * 16384);

#pragma unroll
    for (int j = 0; j < 2; ++j) {
      // ---- S^T = K Q : rows j*64 + {l31, 32+l31} ----
      f32x16 a0 = zero16(), a1 = zero16();
      __builtin_amdgcn_s_setprio(1);
#pragma unroll
      for (int kc = 0; kc < 4; ++kc) {
        int chs = (((kc * 2 + hi) ^ xr ^ xr2)) << 3;
        bf16x8 kA0 = *(const bf16x8*)(kt + (j * 64 + l31) * 64 + chs);
        bf16x8 kA1 = *(const bf16x8*)(kt + (j * 64 + 32 + l31) * 64 + chs);
        a0 = __builtin_amdgcn_mfma_f32_32x32x16_bf16(kA0, qB[kc], a0, 0, 0, 0);
        a1 = __builtin_amdgcn_mfma_f32_32x32x16_bf16(kA1, qB[kc], a1, 0, 0, 0);
      }
      __builtin_amdgcn_s_setprio(0);

      // ---- no-max softmax (exp2 domain) ----
#pragma unroll
      for (int i = 0; i < 16; ++i) a0[i] = exp2fast(a0[i]);
#pragma unroll
      for (int i = 0; i < 16; ++i) a1[i] = exp2fast(a1[i]);
      {
        f32x16 s01 = a0 + a1;
        f32x4 s4;
#pragma unroll
        for (int i = 0; i < 4; ++i)
          s4[i] = (s01[i] + s01[i + 4]) + (s01[i + 8] + s01[i + 12]);
        lrun += (s4[0] + s4[1]) + (s4[2] + s4[3]);
      }

      // ---- P -> PV B-fragments (cvt_pk + permlane32_swap) ----
      bf16x8 pB[4];
#pragma unroll
      for (int sc = 0; sc < 4; ++sc) {
        const f32x16& src = (sc < 2) ? a0 : a1;
        const int rb = (sc & 1) * 8;
        u32 c01 = pk2(src[rb + 0], src[rb + 1]);
        u32 c23 = pk2(src[rb + 2], src[rb + 3]);
        u32 c45 = pk2(src[rb + 4], src[rb + 5]);
        u32 c67 = pk2(src[rb + 6], src[rb + 7]);
        asm volatile("v_permlane32_swap_b32 %0, %1" : "+v"(c01), "+v"(c45));
        asm volatile("v_permlane32_swap_b32 %0, %1" : "+v"(c23), "+v"(c67));
        u32x4 w = {c01, c23, c45, c67};
        pB[sc] = __builtin_bit_cast(bf16x8, w);
      }

      // ---- O^T += V P^T : V rows {l31, 32+l31}, cols j*64.. ----
      __builtin_amdgcn_s_setprio(1);
#pragma unroll
      for (int sc = 0; sc < 4; ++sc) {
        int p = j * 8 + ((sc * 2 + hi) ^ xr ^ xr2);
        bf16x8 vA0 = *(const bf16x8*)(vt + l31 * 128 + p * 8);
        bf16x8 vA1 = *(const bf16x8*)(vt + (32 + l31) * 128 + p * 8);
        oacc0 = __builtin_amdgcn_mfma_f32_32x32x16_bf16(vA0, pB[sc], oacc0, 0, 0, 0);
        oacc1 = __builtin_amdgcn_mfma_f32_32x32x16_bf16(vA1, pB[sc], oacc1, 0, 0, 0);
      }
      __builtin_amdgcn_s_setprio(0);
    }
  }

  // ---- epilogue: direct normalize + store (no merge) ----
  float lfull = lrun + __shfl_xor(lrun, 32);
  float inv = 1.0f / lfull;
  float* outp = out + ((size_t)b * 1024 + (size_t)h * 64) * 2048;
  const int t = q0 + wv * 32 + l31;
#pragma unroll
  for (int r = 0; r < 16; ++r) {
    int c = (r & 3) + 8 * (r >> 2) + 4 * hi;
    outp[(size_t)c * 2048 + t]        = oacc0[r] * inv;
    outp[(size_t)(c + 32) * 2048 + t] = oacc1[r] * inv;
  }
}

// ============ round-1 fallback (no workspace needed) ====================
__global__ __launch_bounds__(256) void qkv_attn_kernel(const float* __restrict__ qkv,
                                                       float* __restrict__ out) {
  __shared__ __align__(16) unsigned short s_kt[64 * 64];
  __shared__ __align__(16) unsigned short s_v [64 * 64];
  __shared__ __align__(16) unsigned short s_qp[128 * 64];

  const int tid  = threadIdx.x;
  const int lane = tid & 63;
  const int wv   = tid >> 6;
  const int l15  = lane & 15;
  const int lg   = lane >> 4;

  int bid = blockIdx.x;
  int bh  = (bid & 7) * 4 + ((bid >> 3) >> 4);
  int qb  = (bid >> 3) & 15;
  int b = bh >> 4, h = bh & 15;
  const float* __restrict__ hq = qkv + ((size_t)b * 3072 + (size_t)h * 192) * 2048;
  const int q0 = qb * 128;

  {
    int c  = (tid & 31) * 2;
    int tq = tid >> 5;
    const float* r0 = hq + (size_t)c * 2048 + q0;
    const float* r1 = r0 + 2048;
#pragma unroll
    for (int j = 0; j < 4; ++j) {
      int t4 = tq * 16 + j * 4;
      f32x4 f0 = *(const f32x4*)(r0 + t4);
      f32x4 f1 = *(const f32x4*)(r1 + t4);
#pragma unroll
      for (int e = 0; e < 4; ++e) {
        int t = t4 + e;
        ((u32*)s_qp)[swz(t, c) >> 1] = packbf2(f0[e] * SCALE, f1[e] * SCALE);
      }
    }
  }
  __syncthreads();

  bf16x8 qA[2][2];
#pragma unroll
  for (int tf = 0; tf < 2; ++tf)
#pragma unroll
    for (int kc = 0; kc < 2; ++kc) {
      int t  = wv * 32 + tf * 16 + l15;
      int c0 = kc * 32 + lg * 8;
      qA[tf][kc] = *(const bf16x8*)&s_qp[swz(t, c0)];
    }

  const f32x4 zf = {0.f, 0.f, 0.f, 0.f};
  f32x4 oacc[2][4];
#pragma unroll
  for (int tf = 0; tf < 2; ++tf)
#pragma unroll
    for (int cs = 0; cs < 4; ++cs) oacc[tf][cs] = zf;
  float mrun[2][4], lrun[2][4];
#pragma unroll
  for (int tf = 0; tf < 2; ++tf)
#pragma unroll
    for (int r = 0; r < 4; ++r) { mrun[tf][r] = -1e30f; lrun[tf][r] = 0.f; }

  const int pw = wv * 2048;

  for (int st = 0; st < 32; ++st) {
    const int s0g = st * 64;
    __syncthreads();
    {
      int c  = (tid & 31) * 2;
      int tq = tid >> 5;
      const float* r0 = hq + (size_t)(64 + c) * 2048 + s0g;
      const float* r1 = r0 + 2048;
#pragma unroll
      for (int j = 0; j < 2; ++j) {
        int s4 = tq * 8 + j * 4;
        f32x4 f0 = *(const f32x4*)(r0 + s4);
        f32x4 f1 = *(const f32x4*)(r1 + s4);
#pragma unroll
        for (int e = 0; e < 4; ++e)
          ((u32*)s_kt)[swz(s4 + e, c) >> 1] = packbf2(f0[e] * SCALE, f1[e] * SCALE);
      }
    }
    {
      int c  = tid >> 2;
      int sq = tid & 3;
      const float* rv = hq + (size_t)(128 + c) * 2048 + s0g;
#pragma unroll
      for (int j = 0; j < 4; ++j) {
        int s4 = sq * 16 + j * 4;
        f32x4 f = *(const f32x4*)(rv + s4);
        int si = swz(c, s4) >> 1;
        ((u32*)s_v)[si]     = packbf2(f[0], f[1]);
        ((u32*)s_v)[si + 1] = packbf2(f[2], f[3]);
      }
    }
    __syncthreads();

    f32x4 acc[2][4];
#pragma unroll
    for (int tf = 0; tf < 2; ++tf)
#pragma unroll
      for (int ss = 0; ss < 4; ++ss) acc[tf][ss] = zf;
#pragma unroll
    for (int kc = 0; kc < 2; ++kc) {
#pragma unroll
      for (int ss = 0; ss < 4; ++ss) {
        int srow = ss * 16 + l15;
        int c0   = kc * 32 + lg * 8;
        bf16x8 kB = *(const bf16x8*)&s_kt[swz(srow, c0)];
#pragma unroll
        for (int tf = 0; tf < 2; ++tf)
          acc[tf][ss] = __builtin_amdgcn_mfma_f32_16x16x32_bf16(qA[tf][kc], kB, acc[tf][ss], 0, 0, 0);
      }
    }

#pragma unroll
    for (int tf = 0; tf < 2; ++tf) {
#pragma unroll
      for (int r = 0; r < 4; ++r) {
        float tm = fmaxf(fmaxf(acc[tf][0][r], acc[tf][1][r]),
                         fmaxf(acc[tf][2][r], acc[tf][3][r]));
#pragma unroll
        for (int off = 1; off < 16; off <<= 1) tm = fmaxf(tm, __shfl_xor(tm, off));
        float mold = mrun[tf][r];
        float mnew = fmaxf(mold, tm);
        float rs   = exp2f((mold - mnew) * LOG2E);
        mrun[tf][r] = mnew;
        int t = tf * 16 + lg * 4 + r;
        float psum = 0.f;
#pragma unroll
        for (int ss = 0; ss < 4; ++ss) {
          float p = exp2f((acc[tf][ss][r] - mnew) * LOG2E);
          psum += p;
          s_qp[pw + swz(t, ss * 16 + l15)] = tobf(p);
        }
        lrun[tf][r] = lrun[tf][r] * rs + psum;
#pragma unroll
        for (int cs = 0; cs < 4; ++cs) oacc[tf][cs][r] *= rs;
      }
    }

    bf16x8 pA[2][2];
#pragma unroll
    for (int tf = 0; tf < 2; ++tf)
#pragma unroll
      for (int kc = 0; kc < 2; ++kc) {
        int t  = tf * 16 + l15;
        int s0 = kc * 32 + lg * 8;
        pA[tf][kc] = *(const bf16x8*)&s_qp[pw + swz(t, s0)];
      }
#pragma unroll
    for (int cs = 0; cs < 4; ++cs) {
#pragma unroll
      for (int kc = 0; kc < 2; ++kc) {
        int crow = cs * 16 + l15;
        int s0   = kc * 32 + lg * 8;
        bf16x8 vB = *(const bf16x8*)&s_v[swz(crow, s0)];
#pragma unroll
        for (int tf = 0; tf < 2; ++tf)
          oacc[tf][cs] = __builtin_amdgcn_mfma_f32_16x16x32_bf16(pA[tf][kc], vB, oacc[tf][cs], 0, 0, 0);
      }
    }
  }

  float* outp = out + ((size_t)b * 1024 + (size_t)h * 64) * 2048;
#pragma unroll
  for (int tf = 0; tf < 2; ++tf) {
    f32x4 invv;
#pragma unroll
    for (int r = 0; r < 4; ++r) {
      float ls = lrun[tf][r];
#pragma unroll
      for (int off = 1; off < 16; off <<= 1) ls += __shfl_xor(ls, off);
      invv[r] = 1.0f / ls;
    }
#pragma unroll
    for (int cs = 0; cs < 4; ++cs) {
      int c = cs * 16 + l15;
      float* po = outp + (size_t)c * 2048 + q0 + wv * 32 + tf * 16 + lg * 4;
      f32x4 o = oacc[tf][cs] * invv;
      *(f32x4*)po = o;
    }
  }
}

extern "C" void kernel_launch(void* const* d_in, const int* in_sizes, int n_in,
                              void* d_out, int out_size, void* d_ws, size_t ws_size,
                              hipStream_t stream) {
  (void)in_sizes; (void)n_in; (void)out_size;
  const float* qkv = (const float*)d_in[0];
  float* outp = (float*)d_out;
  const size_t need = (size_t)96 * 131072 * 2;  // 25.2 MB bf16 workspace
  if (ws_size >= need && d_ws != nullptr) {
    unsigned short* ws = (unsigned short*)d_ws;
    prep_kernel<<<dim3(1024), dim3(256), 0, stream>>>(qkv, ws);
    attn17_kernel<<<dim3(256), dim3(512), 0, stream>>>(ws, outp);
  } else {
    qkv_attn_kernel<<<dim3(512), dim3(256), 0, stream>>>(qkv, outp);
  }
}

// Round 18
// 61.041 us; speedup vs baseline: 3.7087x; 1.3962x over previous
//
#include <hip/hip_runtime.h>
#include <hip/hip_bf16.h>
#include <stdint.h>

typedef float f32x4 __attribute__((ext_vector_type(4)));
typedef float f32x16 __attribute__((ext_vector_type(16)));
typedef __bf16 bf16x8 __attribute__((ext_vector_type(8)));
typedef uint32_t u32;
typedef u32 u32x4 __attribute__((ext_vector_type(4)));

#define SCALE 0.35355339059327378f    // 64^-0.25
#define SCALE2 0.42466090014400953f   // 64^-0.25 * sqrt(log2(e)) -> exp2 domain
#define LOG2E 1.4426950408889634f

// hazard-safe exp2: compiler-emitted v_exp_f32 (TRANS-op wait states handled).
// NOTE: raw inline-asm v_exp_f32 caused deterministic corruption (R6-R8 vs R10/R11 A/B).
#if __has_builtin(__builtin_amdgcn_exp2f)
__device__ __forceinline__ float exp2fast(float x) { return __builtin_amdgcn_exp2f(x); }
#else
__device__ __forceinline__ float exp2fast(float x) { return exp2f(x); }
#endif

__device__ __forceinline__ u32 packbf2(float a, float b) {
  u32 ua = __builtin_bit_cast(u32, a);
  u32 ub = __builtin_bit_cast(u32, b);
  ua = (ua + 0x7fffu + ((ua >> 16) & 1u)) >> 16;
  ub = (ub + 0x7fffu + ((ub >> 16) & 1u)) >> 16;
  return ua | (ub << 16);
}
__device__ __forceinline__ unsigned short tobf(float a) {
  u32 ua = __builtin_bit_cast(u32, a);
  return (unsigned short)((ua + 0x7fffu + ((ua >> 16) & 1u)) >> 16);
}
__device__ __forceinline__ u32 pk2(float a, float b) {
  unsigned short lo = __builtin_bit_cast(unsigned short, (__bf16)a);
  unsigned short hi = __builtin_bit_cast(unsigned short, (__bf16)b);
  return (u32)lo | ((u32)hi << 16);
}
__device__ __forceinline__ int swz(int row, int col) {  // prep-kernel swizzle (8-row stripe)
  return row * 64 + (col ^ ((row & 7) << 3));
}
__device__ __forceinline__ void gload16(const void* g, void* l) {
  __builtin_amdgcn_global_load_lds((const __attribute__((address_space(1))) void*)g,
                                   (__attribute__((address_space(3))) void*)l, 16, 0, 0);
}
__device__ __forceinline__ f32x16 zero16() {
  f32x16 z;
#pragma unroll
  for (int i = 0; i < 16; ++i) z[i] = 0.f;
  return z;
}

// ============ pre-pass: fp32 K,V -> bf16 ws (Q handled in attn) =========
// ws (shorts): [unused Q region 32*131072] | Ks[32][2048][64] | Vs[32][64][2048]
__global__ __launch_bounds__(256) void prep_kernel(const float* __restrict__ qkv,
                                                   unsigned short* __restrict__ ws) {
  __shared__ unsigned short tk[64 * 64];
  const int tid = threadIdx.x;
  const int bid = blockIdx.x;          // 0..1023
  const int bh = bid >> 5;
  const int tile = bid & 31;
  const int b = bh >> 4, h = bh & 15;
  const float* hq = qkv + ((size_t)b * 3072 + (size_t)h * 192) * 2048;
  const int s0 = tile * 64;

  {
    const int c = tid >> 2;
    const int jj = (tid & 3) * 16;
    const float* kp = hq + (size_t)(64 + c) * 2048 + s0 + jj;
    const float* vp = hq + (size_t)(128 + c) * 2048 + s0 + jj;
    unsigned short* vout = ws + (size_t)64 * 131072 + (size_t)bh * 131072 +
                           (size_t)c * 2048 + s0 + jj;
    u32 vbuf[8];
#pragma unroll
    for (int u = 0; u < 4; ++u) {
      f32x4 fk = *(const f32x4*)(kp + u * 4);
      f32x4 fv = *(const f32x4*)(vp + u * 4);
#pragma unroll
      for (int e = 0; e < 4; ++e) {
        int s = jj + u * 4 + e;
        tk[swz(s, c)] = tobf(fk[e] * SCALE2);
      }
      vbuf[2 * u]     = packbf2(fv[0], fv[1]);
      vbuf[2 * u + 1] = packbf2(fv[2], fv[3]);
    }
    *(u32x4*)(vout)     = *(u32x4*)&vbuf[0];
    *(u32x4*)(vout + 8) = *(u32x4*)&vbuf[4];
  }
  __syncthreads();
  {
    const int s = tid >> 2;
    const int c0 = (tid & 3) * 16;
    const int ch0 = (((c0 >> 3) ^ (s & 7)) << 3);
    const int ch1 = ((((c0 >> 3) + 1) ^ (s & 7)) << 3);
    size_t ob = (size_t)bh * 131072 + (size_t)(s0 + s) * 64 + c0;
    unsigned short* kout = ws + (size_t)32 * 131072 + ob;
    *(u32x4*)kout       = *(u32x4*)&tk[s * 64 + ch0];
    *(u32x4*)(kout + 8) = *(u32x4*)&tk[s * 64 + ch1];
  }
}

// ============ attn18: attn15 body verbatim; Q loaded from fp32 input ====
// 512 blocks x 8 waves. Waves 0-3: even KV tiles; waves 4-7: odd KV tiles.
// Stripe-aware LDS swizzle (R15-verified: 0 bank conflicts).
__global__ __launch_bounds__(512, 4) void attn18_kernel(const float* __restrict__ qkv,
                                                        const unsigned short* __restrict__ ws,
                                                        float* __restrict__ out) {
  // smem: [0,32K) K staging grp*16K + buf*8K ; [32K,64K) V same
  //       epilogue reuse: [0,32K) O1 merge [4][64][32] f32; [64K,+512) l [4][32]
  __shared__ __align__(16) char smem[66560];

  const int tid  = threadIdx.x;
  const int lane = tid & 63;
  const int wv   = tid >> 6;       // 0..7
  const int w4   = wv & 3;
  const int grp  = wv >> 2;        // 0: even tiles, 1: odd tiles
  const int l31  = lane & 31;
  const int hi   = lane >> 5;
  const int xr   = l31 & 7;
  const int xr2  = (l31 >> 3) & 3;           // stripe bits of the row being read

  const int bid = blockIdx.x;                    // 0..511
  const int bh  = (bid & 7) * 4 + ((bid >> 3) >> 4);
  const int qb  = (bid >> 3) & 15;
  const int b = bh >> 4, h = bh & 15;

  const unsigned short* Ks = ws + (size_t)32 * 131072 + (size_t)bh * 131072;
  const unsigned short* Vs = ws + (size_t)64 * 131072 + (size_t)bh * 131072;

  // Q as MFMA-B operand, loaded DIRECTLY from fp32 qkv [c][t] (coalesced in t,
  // read exactly once per block -> no prep needed). lane: t=l31, c=kc*16+hi*8+j
  bf16x8 qB[4];
  {
    const float* hq32 = qkv + ((size_t)b * 3072 + (size_t)h * 192) * 2048;
    const int t = qb * 128 + w4 * 32 + l31;
#pragma unroll
    for (int kc = 0; kc < 4; ++kc) {
      u32 w[4];
#pragma unroll
      for (int e = 0; e < 4; ++e) {
        int c0 = kc * 16 + hi * 8 + 2 * e;
        float f0 = hq32[(size_t)c0 * 2048 + t] * SCALE2;
        float f1 = hq32[(size_t)(c0 + 1) * 2048 + t] * SCALE2;
        w[e] = pk2(f0, f1);
      }
      u32x4 wq = {w[0], w[1], w[2], w[3]};
      qB[kc] = __builtin_bit_cast(bf16x8, wq);
    }
  }

  // staging (attn15-verbatim): wave stages rows w4*16+srow (A) and +8 (B);
  // source chunk = (lane&7) ^ (row&7) ^ ((row>>3)&3); LDS dest linear.
  const int srow = lane >> 3;                    // 0..7
  const int xa   = (2 * w4) & 3;
  const int sch0 = (lane & 7) ^ srow ^ xa;
  const int sch1 = sch0 ^ 1;
  const char* kgA = (const char*)Ks + (size_t)(w4 * 16 + srow) * 128      + sch0 * 16;
  const char* kgB = (const char*)Ks + (size_t)(w4 * 16 + 8 + srow) * 128  + sch1 * 16;
  const char* vgA = (const char*)Vs + (size_t)(w4 * 16 + srow) * 4096     + sch0 * 16;
  const char* vgB = (const char*)Vs + (size_t)(w4 * 16 + 8 + srow) * 4096 + sch1 * 16;
  char* kbase = smem + grp * 16384;
  char* vbase = smem + 32768 + grp * 16384;
  char* kd = kbase + w4 * 2048;
  char* vd = vbase + w4 * 2048;

  f32x16 oacc0 = zero16(), oacc1 = zero16();
  float lrun = 0.f;

  { // prologue: stage this group's first tile (st = grp) -> buf 0
    gload16(kgA + (size_t)grp * 8192, kd);
    gload16(kgB + (size_t)grp * 8192, kd + 1024);
    gload16(vgA + (size_t)grp * 128,  vd);
    gload16(vgB + (size_t)grp * 128,  vd + 1024);
  }

#pragma unroll 1
  for (int it = 0; it < 16; ++it) {
    const int cur = it & 1;
    __syncthreads();                 // this group's tile resident in buf[cur]
    if (it < 15) {                   // prefetch next tile of this group
      const int stn = 2 * (it + 1) + grp;
      char* kdn = kd + (cur ^ 1) * 8192;
      char* vdn = vd + (cur ^ 1) * 8192;
      gload16(kgA + (size_t)stn * 8192, kdn);
      gload16(kgB + (size_t)stn * 8192, kdn + 1024);
      gload16(vgA + (size_t)stn * 128,  vdn);
      gload16(vgB + (size_t)stn * 128,  vdn + 1024);
    }

    // ---- S^T = K Q : D[row=s][col=t] ----
    const unsigned short* kt = (const unsigned short*)(kbase + cur * 8192);
    f32x16 a0 = zero16(), a1 = zero16();
    __builtin_amdgcn_s_setprio(1);
#pragma unroll
    for (int kc = 0; kc < 4; ++kc) {
      int chs = (((kc * 2 + hi) ^ xr ^ xr2)) << 3;
      bf16x8 kA0 = *(const bf16x8*)(kt + l31 * 64 + chs);
      bf16x8 kA1 = *(const bf16x8*)(kt + (32 + l31) * 64 + chs);
      a0 = __builtin_amdgcn_mfma_f32_32x32x16_bf16(kA0, qB[kc], a0, 0, 0, 0);
      a1 = __builtin_amdgcn_mfma_f32_32x32x16_bf16(kA1, qB[kc], a1, 0, 0, 0);
    }
    __builtin_amdgcn_s_setprio(0);

    // ---- no-max softmax (exp2 domain): p = exp2(s) directly ----
#pragma unroll
    for (int i = 0; i < 16; ++i) a0[i] = exp2fast(a0[i]);
#pragma unroll
    for (int i = 0; i < 16; ++i) a1[i] = exp2fast(a1[i]);
    {
      f32x16 s01 = a0 + a1;
      f32x4 s4;
#pragma unroll
      for (int i = 0; i < 4; ++i)
        s4[i] = (s01[i] + s01[i + 4]) + (s01[i + 8] + s01[i + 12]);
      lrun += (s4[0] + s4[1]) + (s4[2] + s4[3]);
    }

    // ---- P -> PV B-fragments (cvt_pk + permlane32_swap) ----
    bf16x8 pB[4];
#pragma unroll
    for (int sc = 0; sc < 4; ++sc) {
      const f32x16& src = (sc < 2) ? a0 : a1;
      const int rb = (sc & 1) * 8;
      u32 c01 = pk2(src[rb + 0], src[rb + 1]);
      u32 c23 = pk2(src[rb + 2], src[rb + 3]);
      u32 c45 = pk2(src[rb + 4], src[rb + 5]);
      u32 c67 = pk2(src[rb + 6], src[rb + 7]);
      asm volatile("v_permlane32_swap_b32 %0, %1" : "+v"(c01), "+v"(c45));
      asm volatile("v_permlane32_swap_b32 %0, %1" : "+v"(c23), "+v"(c67));
      u32x4 w = {c01, c23, c45, c67};
      pB[sc] = __builtin_bit_cast(bf16x8, w);
    }

    // ---- O^T += V P^T ----
    const unsigned short* vt = (const unsigned short*)(vbase + cur * 8192);
    __builtin_amdgcn_s_setprio(1);
#pragma unroll
    for (int sc = 0; sc < 4; ++sc) {
      int chs = (((sc * 2 + hi) ^ xr ^ xr2)) << 3;
      bf16x8 vA0 = *(const bf16x8*)(vt + l31 * 64 + chs);
      bf16x8 vA1 = *(const bf16x8*)(vt + (32 + l31) * 64 + chs);
      oacc0 = __builtin_amdgcn_mfma_f32_32x32x16_bf16(vA0, pB[sc], oacc0, 0, 0, 0);
      oacc1 = __builtin_amdgcn_mfma_f32_32x32x16_bf16(vA1, pB[sc], oacc1, 0, 0, 0);
    }
    __builtin_amdgcn_s_setprio(0);
  }

  // ---- epilogue: sum-merge grp0+grp1 (shared zero offset) ----
  float lfull = lrun + __shfl_xor(lrun, 32);
  __syncthreads();                   // staging buffers now reusable
  float* s_O = (float*)smem;                    // [4][64*32]
  float* s_l = (float*)(smem + 65536);          // [4][32]
  if (grp == 1) {
    float* O1 = s_O + w4 * 2048;
#pragma unroll
    for (int r = 0; r < 16; ++r) {
      int c = (r & 3) + 8 * (r >> 2) + 4 * hi;
      O1[c * 32 + l31]        = oacc0[r];
      O1[(c + 32) * 32 + l31] = oacc1[r];
    }
    if (hi == 0) s_l[w4 * 32 + l31] = lfull;
  }
  __syncthreads();
  if (grp == 0) {
    float inv = 1.0f / (lfull + s_l[w4 * 32 + l31]);
    const float* O1 = s_O + w4 * 2048;
    float* outp = out + ((size_t)b * 1024 + (size_t)h * 64) * 2048;
    const int t = qb * 128 + w4 * 32 + l31;
#pragma unroll
    for (int r = 0; r < 16; ++r) {
      int c = (r & 3) + 8 * (r >> 2) + 4 * hi;
      outp[(size_t)c * 2048 + t]        = (oacc0[r] + O1[c * 32 + l31]) * inv;
      outp[(size_t)(c + 32) * 2048 + t] = (oacc1[r] + O1[(c + 32) * 32 + l31]) * inv;
    }
  }
}

// ============ round-1 fallback (no workspace needed) ====================
__global__ __launch_bounds__(256) void qkv_attn_kernel(const float* __restrict__ qkv,
                                                       float* __restrict__ out) {
  __shared__ __align__(16) unsigned short s_kt[64 * 64];
  __shared__ __align__(16) unsigned short s_v [64 * 64];
  __shared__ __align__(16) unsigned short s_qp[128 * 64];

  const int tid  = threadIdx.x;
  const int lane = tid & 63;
  const int wv   = tid >> 6;
  const int l15  = lane & 15;
  const int lg   = lane >> 4;

  int bid = blockIdx.x;
  int bh  = (bid & 7) * 4 + ((bid >> 3) >> 4);
  int qb  = (bid >> 3) & 15;
  int b = bh >> 4, h = bh & 15;
  const float* __restrict__ hq = qkv + ((size_t)b * 3072 + (size_t)h * 192) * 2048;
  const int q0 = qb * 128;

  {
    int c  = (tid & 31) * 2;
    int tq = tid >> 5;
    const float* r0 = hq + (size_t)c * 2048 + q0;
    const float* r1 = r0 + 2048;
#pragma unroll
    for (int j = 0; j < 4; ++j) {
      int t4 = tq * 16 + j * 4;
      f32x4 f0 = *(const f32x4*)(r0 + t4);
      f32x4 f1 = *(const f32x4*)(r1 + t4);
#pragma unroll
      for (int e = 0; e < 4; ++e) {
        int t = t4 + e;
        ((u32*)s_qp)[swz(t, c) >> 1] = packbf2(f0[e] * SCALE, f1[e] * SCALE);
      }
    }
  }
  __syncthreads();

  bf16x8 qA[2][2];
#pragma unroll
  for (int tf = 0; tf < 2; ++tf)
#pragma unroll
    for (int kc = 0; kc < 2; ++kc) {
      int t  = wv * 32 + tf * 16 + l15;
      int c0 = kc * 32 + lg * 8;
      qA[tf][kc] = *(const bf16x8*)&s_qp[swz(t, c0)];
    }

  const f32x4 zf = {0.f, 0.f, 0.f, 0.f};
  f32x4 oacc[2][4];
#pragma unroll
  for (int tf = 0; tf < 2; ++tf)
#pragma unroll
    for (int cs = 0; cs < 4; ++cs) oacc[tf][cs] = zf;
  float mrun[2][4], lrun[2][4];
#pragma unroll
  for (int tf = 0; tf < 2; ++tf)
#pragma unroll
    for (int r = 0; r < 4; ++r) { mrun[tf][r] = -1e30f; lrun[tf][r] = 0.f; }

  const int pw = wv * 2048;

  for (int st = 0; st < 32; ++st) {
    const int s0g = st * 64;
    __syncthreads();
    {
      int c  = (tid & 31) * 2;
      int tq = tid >> 5;
      const float* r0 = hq + (size_t)(64 + c) * 2048 + s0g;
      const float* r1 = r0 + 2048;
#pragma unroll
      for (int j = 0; j < 2; ++j) {
        int s4 = tq * 8 + j * 4;
        f32x4 f0 = *(const f32x4*)(r0 + s4);
        f32x4 f1 = *(const f32x4*)(r1 + s4);
#pragma unroll
        for (int e = 0; e < 4; ++e)
          ((u32*)s_kt)[swz(s4 + e, c) >> 1] = packbf2(f0[e] * SCALE, f1[e] * SCALE);
      }
    }
    {
      int c  = tid >> 2;
      int sq = tid & 3;
      const float* rv = hq + (size_t)(128 + c) * 2048 + s0g;
#pragma unroll
      for (int j = 0; j < 4; ++j) {
        int s4 = sq * 16 + j * 4;
        f32x4 f = *(const f32x4*)(rv + s4);
        int si = swz(c, s4) >> 1;
        ((u32*)s_v)[si]     = packbf2(f[0], f[1]);
        ((u32*)s_v)[si + 1] = packbf2(f[2], f[3]);
      }
    }
    __syncthreads();

    f32x4 acc[2][4];
#pragma unroll
    for (int tf = 0; tf < 2; ++tf)
#pragma unroll
      for (int ss = 0; ss < 4; ++ss) acc[tf][ss] = zf;
#pragma unroll
    for (int kc = 0; kc < 2; ++kc) {
#pragma unroll
      for (int ss = 0; ss < 4; ++ss) {
        int srow = ss * 16 + l15;
        int c0   = kc * 32 + lg * 8;
        bf16x8 kB = *(const bf16x8*)&s_kt[swz(srow, c0)];
#pragma unroll
        for (int tf = 0; tf < 2; ++tf)
          acc[tf][ss] = __builtin_amdgcn_mfma_f32_16x16x32_bf16(qA[tf][kc], kB, acc[tf][ss], 0, 0, 0);
      }
    }

#pragma unroll
    for (int tf = 0; tf < 2; ++tf) {
#pragma unroll
      for (int r = 0; r < 4; ++r) {
        float tm = fmaxf(fmaxf(acc[tf][0][r], acc[tf][1][r]),
                         fmaxf(acc[tf][2][r], acc[tf][3][r]));
#pragma unroll
        for (int off = 1; off < 16; off <<= 1) tm = fmaxf(tm, __shfl_xor(tm, off));
        float mold = mrun[tf][r];
        float mnew = fmaxf(mold, tm);
        float rs   = exp2f((mold - mnew) * LOG2E);
        mrun[tf][r] = mnew;
        int t = tf * 16 + lg * 4 + r;
        float psum = 0.f;
#pragma unroll
        for (int ss = 0; ss < 4; ++ss) {
          float p = exp2f((acc[tf][ss][r] - mnew) * LOG2E);
          psum += p;
          s_qp[pw + swz(t, ss * 16 + l15)] = tobf(p);
        }
        lrun[tf][r] = lrun[tf][r] * rs + psum;
#pragma unroll
        for (int cs = 0; cs < 4; ++cs) oacc[tf][cs][r] *= rs;
      }
    }

    bf16x8 pA[2][2];
#pragma unroll
    for (int tf = 0; tf < 2; ++tf)
#pragma unroll
      for (int kc = 0; kc < 2; ++kc) {
        int t  = tf * 16 + l15;
        int s0 = kc * 32 + lg * 8;
        pA[tf][kc] = *(const bf16x8*)&s_qp[pw + swz(t, s0)];
      }
#pragma unroll
    for (int cs = 0; cs < 4; ++cs) {
#pragma unroll
      for (int kc = 0; kc < 2; ++kc) {
        int crow = cs * 16 + l15;
        int s0   = kc * 32 + lg * 8;
        bf16x8 vB = *(const bf16x8*)&s_v[swz(crow, s0)];
#pragma unroll
        for (int tf = 0; tf < 2; ++tf)
          oacc[tf][cs] = __builtin_amdgcn_mfma_f32_16x16x32_bf16(pA[tf][kc], vB, oacc[tf][cs], 0, 0, 0);
      }
    }
  }

  float* outp = out + ((size_t)b * 1024 + (size_t)h * 64) * 2048;
#pragma unroll
  for (int tf = 0; tf < 2; ++tf) {
    f32x4 invv;
#pragma unroll
    for (int r = 0; r < 4; ++r) {
      float ls = lrun[tf][r];
#pragma unroll
      for (int off = 1; off < 16; off <<= 1) ls += __shfl_xor(ls, off);
      invv[r] = 1.0f / ls;
    }
#pragma unroll
    for (int cs = 0; cs < 4; ++cs) {
      int c = cs * 16 + l15;
      float* po = outp + (size_t)c * 2048 + q0 + wv * 32 + tf * 16 + lg * 4;
      f32x4 o = oacc[tf][cs] * invv;
      *(f32x4*)po = o;
    }
  }
}

extern "C" void kernel_launch(void* const* d_in, const int* in_sizes, int n_in,
                              void* d_out, int out_size, void* d_ws, size_t ws_size,
                              hipStream_t stream) {
  (void)in_sizes; (void)n_in; (void)out_size;
  const float* qkv = (const float*)d_in[0];
  float* outp = (float*)d_out;
  const size_t need = (size_t)96 * 131072 * 2;  // 25.2 MB bf16 workspace
  if (ws_size >= need && d_ws != nullptr) {
    unsigned short* ws = (unsigned short*)d_ws;
    prep_kernel<<<dim3(1024), dim3(256), 0, stream>>>(qkv, ws);
    attn18_kernel<<<dim3(512), dim3(512), 0, stream>>>(qkv, ws, outp);
  } else {
    qkv_attn_kernel<<<dim3(512), dim3(256), 0, stream>>>(qkv, outp);
  }
}